// Round 6
// baseline (178.923 us; speedup 1.0000x reference)
//
#include <hip/hip_runtime.h>
#include <hip/hip_bf16.h>
#include <math.h>

#define T_TOK 2048
#define H_DIM 2048
#define E_EXP 16
#define I_DIM 512
#define TWO_I 1024
#define ROUTED_SCALE 1.5f
#define SWIGLU_LIMIT 7.0f

#define BM 128
#define KC 64
#define MAX_TILES 48
#define PADMAX 6144

typedef __attribute__((ext_vector_type(8))) short bf16x8;
typedef __attribute__((ext_vector_type(4))) float f32x4;
typedef unsigned short u16;

__device__ inline u16 f2bf(float f) {
    return __builtin_bit_cast(u16, __float2bfloat16(f));
}
__device__ inline bf16x8 pack8(float4 a, float4 b) {
    bf16x8 v;
    v[0] = (short)f2bf(a.x); v[1] = (short)f2bf(a.y);
    v[2] = (short)f2bf(a.z); v[3] = (short)f2bf(a.w);
    v[4] = (short)f2bf(b.x); v[5] = (short)f2bf(b.y);
    v[6] = (short)f2bf(b.z); v[7] = (short)f2bf(b.w);
    return v;
}
__device__ inline ushort4 pack4(float4 a) {
    ushort4 v;
    v.x = f2bf(a.x); v.y = f2bf(a.y); v.z = f2bf(a.z); v.w = f2bf(a.w);
    return v;
}

// async 16B global->LDS (lane scatters at ldsbase + lane*16)
__device__ inline void gload16(const u16* g, u16* l) {
    __builtin_amdgcn_global_load_lds(
        (const __attribute__((address_space(1))) void*)(g),
        (__attribute__((address_space(3))) void*)(l), 16, 0, 0);
}

// swizzled ushort index for 64-elem bf16 rows: logical (row,k) -> row*64 + (k ^ ((row&7)<<3))
#define SWZ(row, k) ((row) * 64 + ((k) ^ (((row) & 7) << 3)))

// ---------------- router: one wave per token; also emits hs in bf16 ----------------
__global__ __launch_bounds__(256) void router_kernel(
    const float* __restrict__ hs, const float* __restrict__ gw,
    const float* __restrict__ bias, int* cnt, int* tok_list, float* w_list,
    u16* __restrict__ hs_bf)
{
    int wave = threadIdx.x >> 6;
    int lane = threadIdx.x & 63;
    int t = blockIdx.x * 4 + wave;
    if (t >= T_TOK) return;
    const float* x = hs + (size_t)t * H_DIM;

    float acc[E_EXP];
#pragma unroll
    for (int e = 0; e < E_EXP; ++e) acc[e] = 0.f;

#pragma unroll 2
    for (int c = 0; c < 8; ++c) {
        int col = c * 256 + lane * 4;
        float4 xv = *(const float4*)(x + col);
        *(ushort4*)(hs_bf + (size_t)t * H_DIM + col) = pack4(xv);
#pragma unroll
        for (int e = 0; e < E_EXP; ++e) {
            float4 gv = *(const float4*)(gw + (size_t)e * H_DIM + col);
            acc[e] = fmaf(xv.x, gv.x, acc[e]);
            acc[e] = fmaf(xv.y, gv.y, acc[e]);
            acc[e] = fmaf(xv.z, gv.z, acc[e]);
            acc[e] = fmaf(xv.w, gv.w, acc[e]);
        }
    }
#pragma unroll
    for (int e = 0; e < E_EXP; ++e) {
        for (int m = 32; m >= 1; m >>= 1)
            acc[e] += __shfl_xor(acc[e], m, 64);
    }
    if (lane == 0) {
        float sc[E_EXP], bsc[E_EXP];
#pragma unroll
        for (int e = 0; e < E_EXP; ++e) {
            sc[e] = 1.f / (1.f + expf(-acc[e]));
            bsc[e] = sc[e] + bias[e];
        }
        int e0 = 0; float b0 = bsc[0];
#pragma unroll
        for (int e = 1; e < E_EXP; ++e) if (bsc[e] > b0) { b0 = bsc[e]; e0 = e; }
        int e1 = -1; float b1 = -1e30f;
#pragma unroll
        for (int e = 0; e < E_EXP; ++e) {
            if (e == e0) continue;
            if (bsc[e] > b1) { b1 = bsc[e]; e1 = e; }
        }
        float s0 = sc[e0], s1 = sc[e1];
        float inv = ROUTED_SCALE / (s0 + s1);
        int p0 = atomicAdd(&cnt[e0], 1);
        tok_list[e0 * T_TOK + p0] = t;
        w_list[e0 * T_TOK + p0] = s0 * inv;
        int p1 = atomicAdd(&cnt[e1], 1);
        tok_list[e1 * T_TOK + p1] = t;
        w_list[e1 * T_TOK + p1] = s1 * inv;
    }
}

// ---------------- fused: compact assignments + tile descriptors (BM=128) ----------------
__global__ void scatter_build(const int* __restrict__ cnt,
    const int* __restrict__ tok_list, const float* __restrict__ w_list,
    int* A_tok, float* A_w, int* tile_e, int* tile_r0)
{
    int c[E_EXP], offs[E_EXP + 1];
    offs[0] = 0;
#pragma unroll
    for (int e = 0; e < E_EXP; ++e) {
        c[e] = cnt[e];
        offs[e + 1] = offs[e] + ((c[e] + BM - 1) & ~(BM - 1));
    }
    int idx = blockIdx.x * 256 + threadIdx.x;
    int e = idx >> 11;
    int pos = idx & (T_TOK - 1);
    int ce = c[e];
    int pe = (ce + BM - 1) & ~(BM - 1);
    if (pos < ce) {
        A_tok[offs[e] + pos] = tok_list[idx];
        A_w[offs[e] + pos] = w_list[idx];
    } else if (pos < pe) {
        A_tok[offs[e] + pos] = -1;
        A_w[offs[e] + pos] = 0.f;
    }
    if (idx == 0) {
        int nt = 0;
        for (int ee = 0; ee < E_EXP; ++ee) {
            int ntile = (c[ee] + BM - 1) >> 7;
            for (int j = 0; j < ntile; ++j) {
                tile_e[nt] = ee;
                tile_r0[nt] = offs[ee] + j * BM;
                ++nt;
            }
        }
        for (; nt < MAX_TILES; ++nt) tile_e[nt] = -1;
    }
}

// ---------------- GEMM1: X(128xK bf16, gload_lds) @ w13(64 G + 64 U, fp32 reg-staged)^T ----------------
__global__ __launch_bounds__(256, 2) void gemm1_act(
    const u16* __restrict__ hs_bf, const float* __restrict__ w13,
    const int* __restrict__ A_tok, const int* __restrict__ tile_e,
    const int* __restrict__ tile_r0, u16* __restrict__ act)
{
    int b = blockIdx.x;
    int id = (b & 7) * MAX_TILES + (b >> 3);  // 384 = 8 * 48; XCD x owns y-stripe x
    int tile = id % MAX_TILES;
    int y = id / MAX_TILES;                   // 0..7
    int e = tile_e[tile];
    if (e < 0) return;
    int row0 = tile_r0[tile];
    int i0 = y * 64;
    int tid = threadIdx.x;

    __shared__ u16 Xs[2][8192];   // 128 x 64
    __shared__ u16 Gs[2][4096];   // 64 x 64
    __shared__ u16 Us[2][4096];

    const int l = tid & 63, w = tid >> 6;

    // ---- X staging via global_load_lds: wave w, issues j=0..3 cover rows w*32+j*8..+8 ----
    const int rlo = l >> 3;                  // 0..7
    const int c8 = (l & 7) << 3;
    const int ksrc = c8 ^ (rlo << 3);        // pre-swizzled source k
    const u16* sX[4];
#pragma unroll
    for (int j = 0; j < 4; ++j) {
        int row = w * 32 + j * 8 + rlo;
        int tk = A_tok[row0 + row]; if (tk < 0) tk = 0;   // pad rows masked by A_w=0 downstream
        sX[j] = hs_bf + (size_t)tk * H_DIM + ksrc;
    }
    const int dX = w * 2048;                 // elem offset of wave's 32-row stripe

#define X_STAGE(bb, t) do { int ko = (t) * KC; \
    gload16(sX[0] + ko, &Xs[bb][dX]); \
    gload16(sX[1] + ko, &Xs[bb][dX + 512]); \
    gload16(sX[2] + ko, &Xs[bb][dX + 1024]); \
    gload16(sX[3] + ko, &Xs[bb][dX + 1536]); } while (0)

    // ---- weight staging: dense fp32 loads -> regs -> bf16 -> swizzled ds_write ----
    const int srow = tid >> 2;               // 0..63
    const int c2 = tid & 3;                  // 16-fp32 chunk pair
    const float* gsrc = w13 + ((size_t)e * TWO_I + i0 + srow) * H_DIM + c2 * 16;
    const float* usrc = gsrc + (size_t)I_DIM * H_DIM;
    const int wbA = SWZ(srow, c2 * 16);
    const int wbB = SWZ(srow, c2 * 16 + 8);

    float4 ga0, ga1, gb0, gb1, ua0, ua1, ub0, ub1;
#define W_LOAD(t) do { int k0 = (t) * KC; \
    ga0 = *(const float4*)(gsrc + k0);      ga1 = *(const float4*)(gsrc + k0 + 4); \
    gb0 = *(const float4*)(gsrc + k0 + 8);  gb1 = *(const float4*)(gsrc + k0 + 12); \
    ua0 = *(const float4*)(usrc + k0);      ua1 = *(const float4*)(usrc + k0 + 4); \
    ub0 = *(const float4*)(usrc + k0 + 8);  ub1 = *(const float4*)(usrc + k0 + 12); } while (0)

#define W_WRITE(bb) do { \
    *(bf16x8*)&Gs[bb][wbA] = pack8(ga0, ga1); \
    *(bf16x8*)&Gs[bb][wbB] = pack8(gb0, gb1); \
    *(bf16x8*)&Us[bb][wbA] = pack8(ua0, ua1); \
    *(bf16x8*)&Us[bb][wbB] = pack8(ub0, ub1); } while (0)

    // ---- MFMA roles: 4 waves 2x2; wave tile 64 tok x 32 cols; 4 m-frags x 2 n-frags ----
    const int wm = w >> 1, wn = w & 1;
    const int lr = l & 15, lg = l >> 4;
    int ia[4][2], ib[2][2];
#pragma unroll
    for (int kh = 0; kh < 2; ++kh) {
        int e2 = kh * 32 + lg * 8;
#pragma unroll
        for (int m = 0; m < 4; ++m) ia[m][kh] = SWZ(wm * 64 + m * 16 + lr, e2);
#pragma unroll
        for (int n = 0; n < 2; ++n) ib[n][kh] = SWZ(wn * 32 + n * 16 + lr, e2);
    }

    const f32x4 Z4 = {0.f, 0.f, 0.f, 0.f};
    f32x4 aG[4][2], aU[4][2];
#pragma unroll
    for (int m = 0; m < 4; ++m)
#pragma unroll
        for (int n = 0; n < 2; ++n) { aG[m][n] = Z4; aU[m][n] = Z4; }

    W_LOAD(0);
    X_STAGE(0, 0);
    W_WRITE(0);
    __syncthreads();
    int cur = 0;
    const int NT = H_DIM / KC;               // 32
    for (int t = 0; t < NT; ++t) {
        const bool more = (t + 1 < NT);
        if (more) {
            X_STAGE(cur ^ 1, t + 1);
            W_LOAD(t + 1);
            __builtin_amdgcn_sched_barrier(0);   // pin load-issue before MFMA phase
        }
#pragma unroll
        for (int kh = 0; kh < 2; ++kh) {
            bf16x8 a0 = *(const bf16x8*)&Xs[cur][ia[0][kh]];
            bf16x8 a1 = *(const bf16x8*)&Xs[cur][ia[1][kh]];
            bf16x8 a2 = *(const bf16x8*)&Xs[cur][ia[2][kh]];
            bf16x8 a3 = *(const bf16x8*)&Xs[cur][ia[3][kh]];
            bf16x8 g0 = *(const bf16x8*)&Gs[cur][ib[0][kh]];
            bf16x8 g1 = *(const bf16x8*)&Gs[cur][ib[1][kh]];
            bf16x8 u0 = *(const bf16x8*)&Us[cur][ib[0][kh]];
            bf16x8 u1 = *(const bf16x8*)&Us[cur][ib[1][kh]];
            aG[0][0] = __builtin_amdgcn_mfma_f32_16x16x32_bf16(a0, g0, aG[0][0], 0, 0, 0);
            aG[0][1] = __builtin_amdgcn_mfma_f32_16x16x32_bf16(a0, g1, aG[0][1], 0, 0, 0);
            aG[1][0] = __builtin_amdgcn_mfma_f32_16x16x32_bf16(a1, g0, aG[1][0], 0, 0, 0);
            aG[1][1] = __builtin_amdgcn_mfma_f32_16x16x32_bf16(a1, g1, aG[1][1], 0, 0, 0);
            aG[2][0] = __builtin_amdgcn_mfma_f32_16x16x32_bf16(a2, g0, aG[2][0], 0, 0, 0);
            aG[2][1] = __builtin_amdgcn_mfma_f32_16x16x32_bf16(a2, g1, aG[2][1], 0, 0, 0);
            aG[3][0] = __builtin_amdgcn_mfma_f32_16x16x32_bf16(a3, g0, aG[3][0], 0, 0, 0);
            aG[3][1] = __builtin_amdgcn_mfma_f32_16x16x32_bf16(a3, g1, aG[3][1], 0, 0, 0);
            aU[0][0] = __builtin_amdgcn_mfma_f32_16x16x32_bf16(a0, u0, aU[0][0], 0, 0, 0);
            aU[0][1] = __builtin_amdgcn_mfma_f32_16x16x32_bf16(a0, u1, aU[0][1], 0, 0, 0);
            aU[1][0] = __builtin_amdgcn_mfma_f32_16x16x32_bf16(a1, u0, aU[1][0], 0, 0, 0);
            aU[1][1] = __builtin_amdgcn_mfma_f32_16x16x32_bf16(a1, u1, aU[1][1], 0, 0, 0);
            aU[2][0] = __builtin_amdgcn_mfma_f32_16x16x32_bf16(a2, u0, aU[2][0], 0, 0, 0);
            aU[2][1] = __builtin_amdgcn_mfma_f32_16x16x32_bf16(a2, u1, aU[2][1], 0, 0, 0);
            aU[3][0] = __builtin_amdgcn_mfma_f32_16x16x32_bf16(a3, u0, aU[3][0], 0, 0, 0);
            aU[3][1] = __builtin_amdgcn_mfma_f32_16x16x32_bf16(a3, u1, aU[3][1], 0, 0, 0);
        }
        if (more) W_WRITE(cur ^ 1);          // fp32 load waits land here, after MFMA phase
        __syncthreads();
        cur ^= 1;
    }
#undef X_STAGE
#undef W_LOAD
#undef W_WRITE

#pragma unroll
    for (int m = 0; m < 4; ++m)
#pragma unroll
        for (int n = 0; n < 2; ++n) {
            int col = i0 + wn * 32 + n * 16 + lr;
            int rbase = row0 + wm * 64 + m * 16 + lg * 4;
#pragma unroll
            for (int q = 0; q < 4; ++q) {
                float g = fminf(aG[m][n][q], SWIGLU_LIMIT);
                float u = fminf(fmaxf(aU[m][n][q], -SWIGLU_LIMIT), SWIGLU_LIMIT);
                float s = 1.f / (1.f + __expf(-g));
                act[(size_t)(rbase + q) * I_DIM + col] = f2bf(g * s * u);
            }
        }
}

// ---------------- GEMM2: act(128xK bf16, gload_lds) @ w2(64 rows fp32 reg-staged)^T * comb ----------------
__global__ __launch_bounds__(256, 3) void gemm2_scatter(
    const u16* __restrict__ act, const float* __restrict__ w2,
    const int* __restrict__ A_tok, const float* __restrict__ A_w,
    const int* __restrict__ tile_e, const int* __restrict__ tile_r0,
    float* __restrict__ out)
{
    int b = blockIdx.x;
    int id = (b & 7) * 192 + (b >> 3);       // 1536 = 8 * 192; XCD x owns y in [4x,4x+4)
    int tile = id % MAX_TILES;
    int y = id / MAX_TILES;                  // 0..31
    int e = tile_e[tile];
    if (e < 0) return;
    int row0 = tile_r0[tile];
    int h0 = y * 64;
    int tid = threadIdx.x;

    __shared__ u16 As[2][8192];              // 128 x 64
    __shared__ u16 Bs[2][4096];              // 64 x 64
    __shared__ int toks[BM];
    __shared__ float wts[BM];
    if (tid < BM) { toks[tid] = A_tok[row0 + tid]; wts[tid] = A_w[row0 + tid]; }

    const int l = tid & 63, w = tid >> 6;

    const int rlo = l >> 3;
    const int c8 = (l & 7) << 3;
    const int ksrc = c8 ^ (rlo << 3);
    const u16* sA[4];
#pragma unroll
    for (int j = 0; j < 4; ++j) {
        int row = w * 32 + j * 8 + rlo;
        sA[j] = act + (size_t)(row0 + row) * I_DIM + ksrc;
    }
    const int dA = w * 2048;

#define A_STAGE(bb, t) do { int ko = (t) * KC; \
    gload16(sA[0] + ko, &As[bb][dA]); \
    gload16(sA[1] + ko, &As[bb][dA + 512]); \
    gload16(sA[2] + ko, &As[bb][dA + 1024]); \
    gload16(sA[3] + ko, &As[bb][dA + 1536]); } while (0)

    const int srow = tid >> 2;               // 0..63
    const int c2 = tid & 3;
    const float* bsrc = w2 + ((size_t)e * H_DIM + h0 + srow) * I_DIM + c2 * 16;
    const int wbA = SWZ(srow, c2 * 16);
    const int wbB = SWZ(srow, c2 * 16 + 8);

    float4 ba0, ba1, bb0, bb1;
#define B_LOAD(t) do { int k0 = (t) * KC; \
    ba0 = *(const float4*)(bsrc + k0);      ba1 = *(const float4*)(bsrc + k0 + 4); \
    bb0 = *(const float4*)(bsrc + k0 + 8);  bb1 = *(const float4*)(bsrc + k0 + 12); } while (0)

#define B_WRITE(bb) do { \
    *(bf16x8*)&Bs[bb][wbA] = pack8(ba0, ba1); \
    *(bf16x8*)&Bs[bb][wbB] = pack8(bb0, bb1); } while (0)

    const int wm = w >> 1, wn = w & 1;
    const int lr = l & 15, lg = l >> 4;
    int ia[4][2], ib[2][2];
#pragma unroll
    for (int kh = 0; kh < 2; ++kh) {
        int e2 = kh * 32 + lg * 8;
#pragma unroll
        for (int m = 0; m < 4; ++m) ia[m][kh] = SWZ(wm * 64 + m * 16 + lr, e2);
#pragma unroll
        for (int n = 0; n < 2; ++n) ib[n][kh] = SWZ(wn * 32 + n * 16 + lr, e2);
    }

    const f32x4 Z4 = {0.f, 0.f, 0.f, 0.f};
    f32x4 acc[4][2];
#pragma unroll
    for (int m = 0; m < 4; ++m)
#pragma unroll
        for (int n = 0; n < 2; ++n) acc[m][n] = Z4;

    B_LOAD(0);
    A_STAGE(0, 0);
    B_WRITE(0);
    __syncthreads();
    int cur = 0;
    const int NT = I_DIM / KC;               // 8
    for (int t = 0; t < NT; ++t) {
        const bool more = (t + 1 < NT);
        if (more) {
            A_STAGE(cur ^ 1, t + 1);
            B_LOAD(t + 1);
            __builtin_amdgcn_sched_barrier(0);
        }
#pragma unroll
        for (int kh = 0; kh < 2; ++kh) {
            bf16x8 a0 = *(const bf16x8*)&As[cur][ia[0][kh]];
            bf16x8 a1 = *(const bf16x8*)&As[cur][ia[1][kh]];
            bf16x8 a2 = *(const bf16x8*)&As[cur][ia[2][kh]];
            bf16x8 a3 = *(const bf16x8*)&As[cur][ia[3][kh]];
            bf16x8 b0 = *(const bf16x8*)&Bs[cur][ib[0][kh]];
            bf16x8 b1 = *(const bf16x8*)&Bs[cur][ib[1][kh]];
            acc[0][0] = __builtin_amdgcn_mfma_f32_16x16x32_bf16(a0, b0, acc[0][0], 0, 0, 0);
            acc[0][1] = __builtin_amdgcn_mfma_f32_16x16x32_bf16(a0, b1, acc[0][1], 0, 0, 0);
            acc[1][0] = __builtin_amdgcn_mfma_f32_16x16x32_bf16(a1, b0, acc[1][0], 0, 0, 0);
            acc[1][1] = __builtin_amdgcn_mfma_f32_16x16x32_bf16(a1, b1, acc[1][1], 0, 0, 0);
            acc[2][0] = __builtin_amdgcn_mfma_f32_16x16x32_bf16(a2, b0, acc[2][0], 0, 0, 0);
            acc[2][1] = __builtin_amdgcn_mfma_f32_16x16x32_bf16(a2, b1, acc[2][1], 0, 0, 0);
            acc[3][0] = __builtin_amdgcn_mfma_f32_16x16x32_bf16(a3, b0, acc[3][0], 0, 0, 0);
            acc[3][1] = __builtin_amdgcn_mfma_f32_16x16x32_bf16(a3, b1, acc[3][1], 0, 0, 0);
        }
        if (more) B_WRITE(cur ^ 1);
        __syncthreads();
        cur ^= 1;
    }
#undef A_STAGE
#undef B_LOAD
#undef B_WRITE

#pragma unroll
    for (int m = 0; m < 4; ++m)
#pragma unroll
        for (int n = 0; n < 2; ++n) {
            int col = h0 + wn * 32 + n * 16 + lr;
            int sbase = wm * 64 + m * 16 + lg * 4;
#pragma unroll
            for (int q = 0; q < 4; ++q) {
                int slot = sbase + q;
                int tok = toks[slot];
                if (tok >= 0)
                    atomicAdd(&out[(size_t)tok * H_DIM + col], acc[m][n][q] * wts[slot]);
            }
        }
}

extern "C" void kernel_launch(void* const* d_in, const int* in_sizes, int n_in,
                              void* d_out, int out_size, void* d_ws, size_t ws_size,
                              hipStream_t stream) {
    const float* hs   = (const float*)d_in[0];
    const float* gw   = (const float*)d_in[1];
    const float* bias = (const float*)d_in[2];
    const float* w13  = (const float*)d_in[3];
    const float* w2   = (const float*)d_in[4];
    float* out = (float*)d_out;

    char* ws = (char*)d_ws;
    int*   cnt      = (int*)(ws + 0);          // 64 B
    int*   tile_e   = (int*)(ws + 64);         // 192 B
    int*   tile_r0  = (int*)(ws + 320);        // 192 B (region to 1024)
    int*   tok_list = (int*)(ws + 1024);       // 131072 -> 132096
    float* w_list   = (float*)(ws + 132096);   // 131072 -> 263168
    int*   A_tok    = (int*)(ws + 263168);     // 24576  -> 287744
    float* A_w      = (float*)(ws + 287744);   // 24576  -> 312320
    u16*   act      = (u16*)(ws + 315392);     // 6291456 -> 6606848
    u16*   hs_bf    = (u16*)(ws + 6606848);    // 8388608 -> ~15 MB

    hipMemsetAsync(d_out, 0, (size_t)T_TOK * H_DIM * sizeof(float), stream);
    hipMemsetAsync(cnt, 0, 64, stream);

    router_kernel<<<T_TOK / 4, 256, 0, stream>>>(hs, gw, bias, cnt, tok_list, w_list, hs_bf);
    scatter_build<<<(E_EXP * T_TOK) / 256, 256, 0, stream>>>(cnt, tok_list, w_list, A_tok, A_w, tile_e, tile_r0);

    gemm1_act<<<MAX_TILES * 8, 256, 0, stream>>>(hs_bf, w13, A_tok, tile_e, tile_r0, act);
    gemm2_scatter<<<MAX_TILES * 32, 256, 0, stream>>>(act, w2, A_tok, A_w, tile_e, tile_r0, out);
}